// Round 4
// baseline (530.552 us; speedup 1.0000x reference)
//
#include <hip/hip_runtime.h>
#include <cstdint>
#include <cstddef>

using u16 = unsigned short;
using u32 = unsigned int;

#define DI __device__ __forceinline__

typedef __attribute__((ext_vector_type(8))) short bf16x8;
typedef __attribute__((ext_vector_type(4))) float f32x4;

// bf16 <-> f32 helpers (bit math). Intermediates stored bf16 in ws.
DI float bfu2f(u16 u) { return __uint_as_float(((u32)u) << 16); }
DI u16 f2bu(float f) {  // round-to-nearest-even, finite inputs only
    u32 x = __float_as_uint(f);
    return (u16)((x + 0x7fffu + ((x >> 16) & 1u)) >> 16);
}
DI u32 pk2(float a, float b) { return (u32)f2bu(a) | ((u32)f2bu(b) << 16); }

constexpr int CIN = 512;
constexpr int HW  = 4096;              // 64*64
constexpr size_t PLANE = 16777216ull;  // 8*512*4096 elements per output tensor

// ================= MFMA projection GEMM =================
// Out[M x 32768] = Wcat[M x 512] @ X[512 x (b,4096)] + bias; bf16 out.
__global__ __launch_bounds__(256) void proj_mfma(
    const float* __restrict__ X,
    const float* __restrict__ w0, const float* __restrict__ b0, int n0r,
    const float* __restrict__ w1, const float* __restrict__ b1, int n1r,
    const float* __restrict__ w2, const float* __restrict__ b2,
    u16* __restrict__ o0, u16* __restrict__ o1, u16* __restrict__ o2,
    int o0c, int o1c, int o2c)
{
    __shared__ u16 Wlds[128][40];   // [m][k], rows 80 B (16B-aligned b128)
    __shared__ u16 Xlds[32][136];   // [k][n], rows 272 B (2-way-max banks)
    const int tid = threadIdx.x;
    const int m0  = blockIdx.y * 128;
    const int n0g = blockIdx.x * 128;
    const int b    = n0g >> 12;
    const int col0 = n0g & 4095;
    const float* Xb = X + (size_t)b * CIN * HW;

    const int ml = tid >> 1, wk0 = (tid & 1) * 16;   // W: 16 f32/thread
    const int xk = tid >> 3, xnb = (tid & 7) * 16;   // X: 16 f32/thread
    const int mrow = m0 + ml;
    const float* wr = (mrow < n0r) ? w0 + (size_t)mrow * CIN
                    : (mrow < n0r + n1r) ? w1 + (size_t)(mrow - n0r) * CIN
                    : w2 + (size_t)(mrow - n0r - n1r) * CIN;

    const int lane = tid & 63, wv = tid >> 6;
    const int wm = (wv & 1) * 64, wn = (wv >> 1) * 64;
    const int lr = lane & 15, lq = lane >> 4;

    f32x4 acc[4][4] = {};
    for (int kt = 0; kt < CIN; kt += 32) {
        {
            const float* p = wr + kt + wk0;
            float4 f0 = *(const float4*)(p);
            float4 f1 = *(const float4*)(p + 4);
            float4 f2 = *(const float4*)(p + 8);
            float4 f3 = *(const float4*)(p + 12);
            uint4 u0 = { pk2(f0.x, f0.y), pk2(f0.z, f0.w), pk2(f1.x, f1.y), pk2(f1.z, f1.w) };
            uint4 u1 = { pk2(f2.x, f2.y), pk2(f2.z, f2.w), pk2(f3.x, f3.y), pk2(f3.z, f3.w) };
            *(uint4*)&Wlds[ml][wk0]     = u0;
            *(uint4*)&Wlds[ml][wk0 + 8] = u1;
        }
        {
            const float* p = Xb + (size_t)(kt + xk) * HW + col0 + xnb;
            float4 f0 = *(const float4*)(p);
            float4 f1 = *(const float4*)(p + 4);
            float4 f2 = *(const float4*)(p + 8);
            float4 f3 = *(const float4*)(p + 12);
            uint4 u0 = { pk2(f0.x, f0.y), pk2(f0.z, f0.w), pk2(f1.x, f1.y), pk2(f1.z, f1.w) };
            uint4 u1 = { pk2(f2.x, f2.y), pk2(f2.z, f2.w), pk2(f3.x, f3.y), pk2(f3.z, f3.w) };
            *(uint4*)&Xlds[xk][xnb]     = u0;
            *(uint4*)&Xlds[xk][xnb + 8] = u1;
        }
        __syncthreads();
        bf16x8 a[4];
        #pragma unroll
        for (int i = 0; i < 4; i++)
            a[i] = *(const bf16x8*)&Wlds[wm + i * 16 + lr][lq * 8];
        #pragma unroll
        for (int j = 0; j < 4; j++) {
            bf16x8 bv;
            const int nn = wn + j * 16 + lr;
            #pragma unroll
            for (int jj = 0; jj < 8; jj++) bv[jj] = (short)Xlds[lq * 8 + jj][nn];
            #pragma unroll
            for (int i = 0; i < 4; i++)
                acc[i][j] = __builtin_amdgcn_mfma_f32_16x16x32_bf16(a[i], bv, acc[i][j], 0, 0, 0);
        }
        __syncthreads();
    }
    #pragma unroll
    for (int i = 0; i < 4; i++) {
        const int mbase = m0 + wm + i * 16;
        const float* bp; u16* op; int ch0, cc;
        if (mbase < n0r)             { bp = b0; op = o0; ch0 = mbase;             cc = o0c; }
        else if (mbase < n0r + n1r)  { bp = b1; op = o1; ch0 = mbase - n0r;       cc = o1c; }
        else                         { bp = b2; op = o2; ch0 = mbase - n0r - n1r; cc = o2c; }
        #pragma unroll
        for (int r = 0; r < 4; r++) {
            const int ch = ch0 + lq * 4 + r;
            const float bias = bp[ch];
            #pragma unroll
            for (int j = 0; j < 4; j++) {
                const int colx = col0 + wn + j * 16 + lr;
                op[((size_t)b * cc + ch) * HW + colx] = f2bu(acc[i][j][r] + bias);
            }
        }
    }
}

// ============== 64x64 last-two-dims transpose (bf16 -> bf16) ==============
__global__ __launch_bounds__(256) void transpose64_bb(
    const u16* __restrict__ src, u16* __restrict__ dst)
{
    __shared__ u16 t[64][65];
    const size_t s = blockIdx.x;
    const u16* sp = src + s * 4096;
    u16* dp = dst + s * 4096;
    const int tid = threadIdx.x;
    #pragma unroll
    for (int i = 0; i < 16; i++) { int idx = tid + 256 * i; t[idx >> 6][idx & 63] = sp[idx]; }
    __syncthreads();
    #pragma unroll
    for (int i = 0; i < 16; i++) { int idx = tid + 256 * i; dp[idx] = t[idx & 63][idx >> 6]; }
}

// ============== in-place per-slice 64x64 bf16 transpose ==============
__global__ __launch_bounds__(256) void transpose64_bb_inplace(u16* __restrict__ d)
{
    __shared__ u16 t[64][65];
    u16* p = d + (size_t)blockIdx.x * 4096;
    const int tid = threadIdx.x;
    #pragma unroll
    for (int i = 0; i < 16; i++) { int idx = tid + 256 * i; t[idx >> 6][idx & 63] = p[idx]; }
    __syncthreads();
    #pragma unroll
    for (int i = 0; i < 16; i++) { int idx = tid + 256 * i; p[idx] = t[idx & 63][idx >> 6]; }
}

// ============== channel-last transpose: [64][4096] -> [4096][64] ==========
__global__ __launch_bounds__(256) void transpose_cl(
    const u16* __restrict__ src, u16* __restrict__ dst)
{
    __shared__ u16 t[64][65];
    const int s = blockIdx.x;
    const int batch = s >> 6, tile = s & 63;
    const u16* sp = src + (size_t)batch * 262144 + (size_t)tile * 64;
    u16* dp = dst + (size_t)batch * 262144 + (size_t)tile * 4096;
    const int tid = threadIdx.x;
    {
        const int c = tid >> 2, x0 = (tid & 3) * 16;
        *(uint4*)&t[c][x0]     = *(const uint4*)(sp + (size_t)c * 4096 + x0);
        *(uint4*)&t[c][x0 + 8] = *(const uint4*)(sp + (size_t)c * 4096 + x0 + 8);
    }
    __syncthreads();
    {
        const int x = tid >> 2, c0 = (tid & 3) * 16;
        u16 tmp[16];
        #pragma unroll
        for (int i = 0; i < 16; i++) tmp[i] = t[c0 + i][x];
        *(uint4*)&dp[(size_t)x * 64 + c0]     = *(uint4*)&tmp[0];
        *(uint4*)&dp[(size_t)x * 64 + c0 + 8] = *(uint4*)&tmp[8];
    }
}

// ======================= energies (MFMA) =======================
// e layout: (b,h,w,128) fp32. [0:64) = energy_H, [64:128) = energy_W.
// qc/kc: channel-last (b, h*64+w, 64c) bf16.
__global__ __launch_bounds__(256) void energy_h_mfma(
    const u16* __restrict__ qc, const u16* __restrict__ kc, float* __restrict__ e)
{
    __shared__ u16 Qs[64][72], Ks[64][72];  // [h][c] rows 144B
    const int w = blockIdx.x, b = blockIdx.y;
    const int tid = threadIdx.x;
    {
        const int row = tid >> 2, ch = (tid & 3) * 16;
        const size_t g = ((size_t)b * 4096 + (size_t)row * 64 + w) * 64 + ch;
        *(uint4*)&Qs[row][ch]     = *(const uint4*)(qc + g);
        *(uint4*)&Qs[row][ch + 8] = *(const uint4*)(qc + g + 8);
        *(uint4*)&Ks[row][ch]     = *(const uint4*)(kc + g);
        *(uint4*)&Ks[row][ch + 8] = *(const uint4*)(kc + g + 8);
    }
    __syncthreads();
    const int lane = tid & 63, wv = tid >> 6;
    const int mH = (wv & 1) * 32, nh = (wv >> 1) * 32;
    const int lr = lane & 15, lq = lane >> 4;
    f32x4 acc[2][2] = {};
    #pragma unroll
    for (int kt = 0; kt < 2; kt++) {
        const int k0 = kt * 32 + lq * 8;
        bf16x8 afr[2], bfr[2];
        #pragma unroll
        for (int i = 0; i < 2; i++) afr[i] = *(const bf16x8*)&Ks[mH + i * 16 + lr][k0];
        #pragma unroll
        for (int j = 0; j < 2; j++) bfr[j] = *(const bf16x8*)&Qs[nh + j * 16 + lr][k0];
        #pragma unroll
        for (int j = 0; j < 2; j++)
            #pragma unroll
            for (int i = 0; i < 2; i++)
                acc[i][j] = __builtin_amdgcn_mfma_f32_16x16x32_bf16(afr[i], bfr[j], acc[i][j], 0, 0, 0);
    }
    #pragma unroll
    for (int i = 0; i < 2; i++)
        #pragma unroll
        for (int j = 0; j < 2; j++) {
            const int h = nh + j * 16 + lr;
            const int Hp = mH + i * 16 + lq * 4;
            float4 v = make_float4(acc[i][j][0], acc[i][j][1], acc[i][j][2], acc[i][j][3]);
            *reinterpret_cast<float4*>(e + ((size_t)(b * 64 + h) * 64 + w) * 128 + Hp) = v;
        }
}

__global__ __launch_bounds__(256) void energy_w_mfma(
    const u16* __restrict__ qc, const u16* __restrict__ kc, float* __restrict__ e)
{
    __shared__ u16 Qs[64][72], Ks[64][72];  // [w][c]
    const int h = blockIdx.x, b = blockIdx.y;
    const int tid = threadIdx.x;
    {
        const int row = tid >> 2, ch = (tid & 3) * 16;
        const size_t g = ((size_t)b * 4096 + (size_t)h * 64 + row) * 64 + ch;
        *(uint4*)&Qs[row][ch]     = *(const uint4*)(qc + g);
        *(uint4*)&Qs[row][ch + 8] = *(const uint4*)(qc + g + 8);
        *(uint4*)&Ks[row][ch]     = *(const uint4*)(kc + g);
        *(uint4*)&Ks[row][ch + 8] = *(const uint4*)(kc + g + 8);
    }
    __syncthreads();
    const int lane = tid & 63, wv = tid >> 6;
    const int mW = (wv & 1) * 32, nw = (wv >> 1) * 32;
    const int lr = lane & 15, lq = lane >> 4;
    f32x4 acc[2][2] = {};
    #pragma unroll
    for (int kt = 0; kt < 2; kt++) {
        const int k0 = kt * 32 + lq * 8;
        bf16x8 afr[2], bfr[2];
        #pragma unroll
        for (int i = 0; i < 2; i++) afr[i] = *(const bf16x8*)&Ks[mW + i * 16 + lr][k0];
        #pragma unroll
        for (int j = 0; j < 2; j++) bfr[j] = *(const bf16x8*)&Qs[nw + j * 16 + lr][k0];
        #pragma unroll
        for (int j = 0; j < 2; j++)
            #pragma unroll
            for (int i = 0; i < 2; i++)
                acc[i][j] = __builtin_amdgcn_mfma_f32_16x16x32_bf16(afr[i], bfr[j], acc[i][j], 0, 0, 0);
    }
    #pragma unroll
    for (int i = 0; i < 2; i++)
        #pragma unroll
        for (int j = 0; j < 2; j++) {
            const int w = nw + j * 16 + lr;
            const int Wp = mW + i * 16 + lq * 4;
            float4 v = make_float4(acc[i][j][0], acc[i][j][1], acc[i][j][2], acc[i][j][3]);
            *reinterpret_cast<float4*>(e + ((size_t)(b * 64 + h) * 64 + w) * 128 + 64 + Wp) = v;
        }
}

// ============ softmax over 128, f32 in -> bf16 out ============
__global__ __launch_bounds__(256) void softmax128_bf(
    const float* __restrict__ e, u16* __restrict__ attb)
{
    const int pos = blockIdx.x * 4 + (threadIdx.x >> 6);
    const int l = threadIdx.x & 63;
    const float* p = e + (size_t)pos * 128;
    float v0 = p[l], v1 = p[l + 64];
    float m = fmaxf(v0, v1);
    #pragma unroll
    for (int o = 32; o > 0; o >>= 1) m = fmaxf(m, __shfl_xor(m, o, 64));
    float e0 = __expf(v0 - m), e1 = __expf(v1 - m);
    float s = e0 + e1;
    #pragma unroll
    for (int o = 32; o > 0; o >>= 1) s += __shfl_xor(s, o, 64);
    float inv = 1.0f / s;
    u16* q = attb + (size_t)pos * 128;
    q[l] = f2bu(e0 * inv);
    q[l + 64] = f2bu(e1 * inv);
}

// ======================= H-aggregation (MFMA, LDS-staged, in-place) =======
// P[b,c,w,h] = sum_H' vT[b,c,w,H'] * attH[b,h,w,H'].  Round-2 orientation
// (D row = c, col = h), c-tile 64 -> LDS 18.4 KB, 8 blocks/CU possible.
// grid (mt=16, w=64, b=8). mt 0-7 -> a-side (c0=(mt&7)*64), 8-15 -> b-side.
__global__ __launch_bounds__(256) void agg_h_mfma(
    const u16* __restrict__ vTa, const u16* __restrict__ vTb,
    const u16* __restrict__ attb, u16* __restrict__ Pa, u16* __restrict__ Pb)
{
    __shared__ u16 Vs[64][72];   // [c][H'], rows 144 B
    __shared__ u16 As[64][72];   // [h][H']
    const int mt = blockIdx.x, w = blockIdx.y, b = blockIdx.z;
    const u16* vT = (mt < 8) ? vTa : vTb;
    u16*       P  = (mt < 8) ? Pa  : Pb;
    const int c0 = (mt & 7) * 64;
    const int tid = threadIdx.x;
    const u16* va = vT + ((size_t)(b * 512 + c0) * 64 + w) * 64;          // + c*4096 + H'
    const u16* ab = attb + ((size_t)b * 4096 + w) * 128;                  // + h*8192 + H'
    {
        const int r = tid >> 3, cB = (tid & 7) * 8;
        #pragma unroll
        for (int i = 0; i < 2; i++)
            *(uint4*)&Vs[r + 32 * i][cB] = *(const uint4*)(va + (size_t)(r + 32 * i) * 4096 + cB);
        #pragma unroll
        for (int i = 0; i < 2; i++)
            *(uint4*)&As[r + 32 * i][cB] = *(const uint4*)(ab + (size_t)(r + 32 * i) * 8192 + cB);
    }
    __syncthreads();
    const int lane = tid & 63, wv = tid >> 6;
    const int wc = (wv & 1) * 32, wh = (wv >> 1) * 32;
    const int lr = lane & 15, lq = lane >> 4;
    f32x4 acc[2][2] = {};
    #pragma unroll
    for (int kt = 0; kt < 2; kt++) {
        const int k0 = kt * 32 + lq * 8;
        bf16x8 afr[2], bfr[2];
        #pragma unroll
        for (int i = 0; i < 2; i++) afr[i] = *(const bf16x8*)&Vs[wc + i * 16 + lr][k0];
        #pragma unroll
        for (int j = 0; j < 2; j++) bfr[j] = *(const bf16x8*)&As[wh + j * 16 + lr][k0];
        #pragma unroll
        for (int j = 0; j < 2; j++)
            #pragma unroll
            for (int i = 0; i < 2; i++)
                acc[i][j] = __builtin_amdgcn_mfma_f32_16x16x32_bf16(afr[i], bfr[j], acc[i][j], 0, 0, 0);
    }
    // D: row(c within 16-tile) = lq*4+r, col(h) = lr
    #pragma unroll
    for (int i = 0; i < 2; i++)
        #pragma unroll
        for (int j = 0; j < 2; j++) {
            u16* pp = P + ((size_t)(b * 512 + c0 + wc + i * 16 + lq * 4) * 64 + w) * 64 + wh + j * 16 + lr;
            #pragma unroll
            for (int r = 0; r < 4; r++) pp[(size_t)r * 4096] = f2bu(acc[i][j][r]);
        }
}

// ======================= W-aggregation (MFMA, LDS-staged) + epilogue ======
// Round-2 orientation (D row = c, col = w), c-tile 64.
// y = g*(P + OutW) + x   (P in (b,c,h,w) bf16, x/y f32)
__global__ __launch_bounds__(256) void agg_w_mfma(
    const u16* __restrict__ v2, const u16* __restrict__ v1,
    const u16* __restrict__ P2, const u16* __restrict__ P1,
    const u16* __restrict__ attb,
    const float* __restrict__ x2, const float* __restrict__ x1,
    const float* __restrict__ gptr, float* __restrict__ out)
{
    __shared__ u16 Vs[64][72];   // [c][W']
    __shared__ u16 As[64][72];   // [w][W']
    const int mt = blockIdx.x, h = blockIdx.y, b = blockIdx.z;
    const u16* v = (mt < 8) ? v2 : v1;
    const u16* P = (mt < 8) ? P2 : P1;
    const float* x = (mt < 8) ? x2 : x1;
    float* y = out + ((mt < 8) ? 0 : PLANE);
    const int c0 = (mt & 7) * 64;
    const int tid = threadIdx.x;
    const u16* vb = v + (size_t)(b * 512 + c0) * 4096 + h * 64;           // + c*4096 + W'
    const u16* ab = attb + ((size_t)(b * 64 + h) * 64) * 128 + 64;        // + w*128 + W'
    {
        const int r = tid >> 3, cB = (tid & 7) * 8;
        #pragma unroll
        for (int i = 0; i < 2; i++)
            *(uint4*)&Vs[r + 32 * i][cB] = *(const uint4*)(vb + (size_t)(r + 32 * i) * 4096 + cB);
        #pragma unroll
        for (int i = 0; i < 2; i++)
            *(uint4*)&As[r + 32 * i][cB] = *(const uint4*)(ab + (size_t)(r + 32 * i) * 128 + cB);
    }
    __syncthreads();
    const int lane = tid & 63, wv = tid >> 6;
    const int wc = (wv & 1) * 32, ww = (wv >> 1) * 32;
    const int lr = lane & 15, lq = lane >> 4;
    f32x4 acc[2][2] = {};
    #pragma unroll
    for (int kt = 0; kt < 2; kt++) {
        const int k0 = kt * 32 + lq * 8;
        bf16x8 afr[2], bfr[2];
        #pragma unroll
        for (int i = 0; i < 2; i++) afr[i] = *(const bf16x8*)&Vs[wc + i * 16 + lr][k0];
        #pragma unroll
        for (int j = 0; j < 2; j++) bfr[j] = *(const bf16x8*)&As[ww + j * 16 + lr][k0];
        #pragma unroll
        for (int j = 0; j < 2; j++)
            #pragma unroll
            for (int i = 0; i < 2; i++)
                acc[i][j] = __builtin_amdgcn_mfma_f32_16x16x32_bf16(afr[i], bfr[j], acc[i][j], 0, 0, 0);
    }
    const float g = gptr[0];
    // D: row(c) = lq*4+r, col(w) = lr
    #pragma unroll
    for (int i = 0; i < 2; i++)
        #pragma unroll
        for (int j = 0; j < 2; j++) {
            size_t off = (size_t)(b * 512 + c0 + wc + i * 16 + lq * 4) * 4096
                       + (size_t)h * 64 + ww + j * 16 + lr;
            #pragma unroll
            for (int r = 0; r < 4; r++) {
                size_t o = off + (size_t)r * 4096;
                y[o] = g * (bfu2f(P[o]) + acc[i][j][r]) + x[o];
            }
        }
}

// ======================= host =======================
extern "C" void kernel_launch(void* const* d_in, const int* in_sizes, int n_in,
                              void* d_out, int out_size, void* d_ws, size_t ws_size,
                              hipStream_t stream)
{
    (void)in_sizes; (void)n_in; (void)out_size; (void)ws_size;
    const float* x2  = (const float*)d_in[0];
    const float* x1  = (const float*)d_in[1];
    const float* q_w = (const float*)d_in[2];
    const float* q_b = (const float*)d_in[3];
    const float* k_w = (const float*)d_in[4];
    const float* k_b = (const float*)d_in[5];
    const float* v_w = (const float*)d_in[6];
    const float* v_b = (const float*)d_in[7];
    const float* gm  = (const float*)d_in[8];

    // ws (MiB): v2 0-32 | v1 32-64 | attb 64-72 |
    //   scratch (dead after softmax): q 72-76 | k 76-80 | qc 80-84 | kc 84-88 | e 88-104
    //   vT2/P2 72-104, vT1/P1 104-136 (written after softmax; overlay scratch)
    // Total: 136 MiB.
    char* ws = (char*)d_ws;
    u16*   v2   = (u16*)(ws);
    u16*   v1   = (u16*)(ws + ((size_t)32  << 20));
    u16*   attb = (u16*)(ws + ((size_t)64  << 20));
    u16*   q    = (u16*)(ws + ((size_t)72  << 20));
    u16*   k    = (u16*)(ws + ((size_t)76  << 20));
    u16*   qc   = (u16*)(ws + ((size_t)80  << 20));
    u16*   kc   = (u16*)(ws + ((size_t)84  << 20));
    float* e    = (float*)(ws + ((size_t)88 << 20));
    u16*   vT2  = (u16*)(ws + ((size_t)72  << 20));  // overlays q..e (dead by then)
    u16*   vT1  = (u16*)(ws + ((size_t)104 << 20));
    float* out = (float*)d_out;

    dim3 blk(256);
    // fused q/k/v2 projection from x2 (M=640), v1 from x1 (M=512)
    proj_mfma<<<dim3(256, 5), blk, 0, stream>>>(x2, q_w, q_b, 64, k_w, k_b, 64,
                                                v_w, v_b, q, k, v2, 64, 64, 512);
    proj_mfma<<<dim3(256, 4), blk, 0, stream>>>(x1, v_w, v_b, 0, v_w, v_b, 0,
                                                v_w, v_b, q, k, v1, 64, 64, 512);
    transpose_cl<<<1024, blk, 0, stream>>>(q, qc);          // q+k -> qc+kc (channel-last)
    energy_h_mfma<<<dim3(64, 8), blk, 0, stream>>>(qc, kc, e);
    energy_w_mfma<<<dim3(64, 8), blk, 0, stream>>>(qc, kc, e);
    softmax128_bf<<<8192, blk, 0, stream>>>(e, attb);       // e dead after this
    transpose64_bb<<<8192, blk, 0, stream>>>(v2, vT2);      // v2+v1 -> vT2+vT1
    agg_h_mfma<<<dim3(16, 64, 8), blk, 0, stream>>>(vT2, vT1, attb, vT2, vT1); // P over vT
    transpose64_bb_inplace<<<8192, blk, 0, stream>>>(vT2);  // P -> (b,c,h,w)
    agg_w_mfma<<<dim3(16, 64, 8), blk, 0, stream>>>(v2, v1, vT2, vT1, attb,
                                                    x2, x1, gm, out);
}

// Round 5
// 499.273 us; speedup vs baseline: 1.0626x; 1.0626x over previous
//
#include <hip/hip_runtime.h>
#include <cstdint>
#include <cstddef>

using u16 = unsigned short;
using u32 = unsigned int;

#define DI __device__ __forceinline__

typedef __attribute__((ext_vector_type(8))) short bf16x8;
typedef __attribute__((ext_vector_type(4))) float f32x4;

// bf16 <-> f32 helpers (bit math). Intermediates stored bf16 in ws.
DI float bfu2f(u16 u) { return __uint_as_float(((u32)u) << 16); }
DI u16 f2bu(float f) {  // round-to-nearest-even, finite inputs only
    u32 x = __float_as_uint(f);
    return (u16)((x + 0x7fffu + ((x >> 16) & 1u)) >> 16);
}
DI u32 pk2(float a, float b) { return (u32)f2bu(a) | ((u32)f2bu(b) << 16); }

constexpr int CIN = 512;
constexpr int HW  = 4096;              // 64*64
constexpr size_t PLANE = 16777216ull;  // 8*512*4096 elements per output tensor

// ================= MFMA projection GEMM (merged, Xᵀ-in-LDS) =================
// Rows m = 0..1151 of Wcat: [0,64)=q, [64,128)=k, [128,640)=v2 (from x2),
// [640,1152)=v1 (from x1).  D[n][m] per block tile: A = Xᵀ (b128 rows),
// B = W (b128 rows), packed uint2 stores of 4 consecutive spatial cols.
// grid (256 n-tiles, 9 m-tiles), block 256 (4 waves), BK=32.
__global__ __launch_bounds__(256) void proj_mfma(
    const float* __restrict__ x2, const float* __restrict__ x1,
    const float* __restrict__ q_w, const float* __restrict__ q_b,
    const float* __restrict__ k_w, const float* __restrict__ k_b,
    const float* __restrict__ v_w, const float* __restrict__ v_b,
    u16* __restrict__ oq, u16* __restrict__ ok,
    u16* __restrict__ ov2, u16* __restrict__ ov1)
{
    __shared__ u16 Wlds[128][40];   // [m][k], rows 80 B (b128 reads 2-way-free)
    __shared__ u16 Xlds[128][40];   // [n][k], Xᵀ tile, same geometry
    const int tid = threadIdx.x;
    const int m0  = blockIdx.y * 128;          // 0..1151
    const int n0g = blockIdx.x * 128;
    const int b    = n0g >> 12;
    const int col0 = n0g & 4095;
    const float* Xb = ((m0 < 640) ? x2 : x1) + (size_t)b * CIN * HW;

    // stager roles: threads 0-127 stage Xᵀ (row n), 128-255 stage W (row m)
    const bool isX = tid < 128;
    const int sr = tid & 127;
    const int mrow = m0 + sr;
    const float* wr;
    if (mrow < 64)        wr = q_w + (size_t)mrow * CIN;
    else if (mrow < 128)  wr = k_w + (size_t)(mrow - 64) * CIN;
    else if (mrow < 640)  wr = v_w + (size_t)(mrow - 128) * CIN;
    else                  wr = v_w + (size_t)(mrow - 640) * CIN;

    const int lane = tid & 63, wv = tid >> 6;
    const int wn = (wv & 1) * 64;   // n-offset (D rows)
    const int wm = (wv >> 1) * 64;  // m-offset (D cols)
    const int lr = lane & 15, lq = lane >> 4;

    f32x4 acc[4][4] = {};           // [i: n-frag][j: m-frag]
    for (int kt = 0; kt < CIN; kt += 32) {
        if (isX) {
            // Xᵀ stage: lane-coalesced along n, per-lane walk along k.
            const float* px = Xb + (size_t)kt * HW + col0 + sr;
            u32 pkv[16];
            #pragma unroll
            for (int kk = 0; kk < 16; kk++) {
                float a = px[(size_t)(2 * kk) * HW];
                float c = px[(size_t)(2 * kk + 1) * HW];
                pkv[kk] = pk2(a, c);
            }
            *(uint4*)&Xlds[sr][0]  = *(uint4*)&pkv[0];
            *(uint4*)&Xlds[sr][8]  = *(uint4*)&pkv[4];
            *(uint4*)&Xlds[sr][16] = *(uint4*)&pkv[8];
            *(uint4*)&Xlds[sr][24] = *(uint4*)&pkv[12];
        } else {
            const float* p = wr + kt;
            u32 pw[16];
            #pragma unroll
            for (int t = 0; t < 8; t++) {
                float4 f = *(const float4*)(p + 4 * t);
                pw[2 * t]     = pk2(f.x, f.y);
                pw[2 * t + 1] = pk2(f.z, f.w);
            }
            *(uint4*)&Wlds[sr][0]  = *(uint4*)&pw[0];
            *(uint4*)&Wlds[sr][8]  = *(uint4*)&pw[4];
            *(uint4*)&Wlds[sr][16] = *(uint4*)&pw[8];
            *(uint4*)&Wlds[sr][24] = *(uint4*)&pw[12];
        }
        __syncthreads();
        bf16x8 a[4], bb[4];
        #pragma unroll
        for (int i = 0; i < 4; i++)
            a[i] = *(const bf16x8*)&Xlds[wn + i * 16 + lr][lq * 8];
        #pragma unroll
        for (int j = 0; j < 4; j++)
            bb[j] = *(const bf16x8*)&Wlds[wm + j * 16 + lr][lq * 8];
        #pragma unroll
        for (int j = 0; j < 4; j++)
            #pragma unroll
            for (int i = 0; i < 4; i++)
                acc[i][j] = __builtin_amdgcn_mfma_f32_16x16x32_bf16(a[i], bb[j], acc[i][j], 0, 0, 0);
        __syncthreads();
    }
    // epilogue: D row = n (lq*4+r consecutive), col = m (lr). Per-j routing
    // (frag m-base multiple of 16; boundaries 64/128/640 never split a frag).
    #pragma unroll
    for (int j = 0; j < 4; j++) {
        const int mbase = m0 + wm + j * 16;
        const float* bp; u16* op; int ch0, cc;
        if (mbase < 64)       { bp = q_b; op = oq;  ch0 = mbase;       cc = 64;  }
        else if (mbase < 128) { bp = k_b; op = ok;  ch0 = mbase - 64;  cc = 64;  }
        else if (mbase < 640) { bp = v_b; op = ov2; ch0 = mbase - 128; cc = 512; }
        else                  { bp = v_b; op = ov1; ch0 = mbase - 640; cc = 512; }
        const int ch = ch0 + lr;
        const float bias = bp[ch];
        u16* obase = op + ((size_t)b * cc + ch) * HW + col0 + wn + lq * 4;
        #pragma unroll
        for (int i = 0; i < 4; i++) {
            uint2 pkd = { pk2(acc[i][j][0] + bias, acc[i][j][1] + bias),
                          pk2(acc[i][j][2] + bias, acc[i][j][3] + bias) };
            *(uint2*)(obase + i * 16) = pkd;
        }
    }
}

// ============== 64x64 last-two-dims transpose (bf16 -> bf16) ==============
__global__ __launch_bounds__(256) void transpose64_bb(
    const u16* __restrict__ src, u16* __restrict__ dst)
{
    __shared__ u16 t[64][65];
    const size_t s = blockIdx.x;
    const u16* sp = src + s * 4096;
    u16* dp = dst + s * 4096;
    const int tid = threadIdx.x;
    #pragma unroll
    for (int i = 0; i < 16; i++) { int idx = tid + 256 * i; t[idx >> 6][idx & 63] = sp[idx]; }
    __syncthreads();
    #pragma unroll
    for (int i = 0; i < 16; i++) { int idx = tid + 256 * i; dp[idx] = t[idx & 63][idx >> 6]; }
}

// ============== in-place per-slice 64x64 bf16 transpose ==============
__global__ __launch_bounds__(256) void transpose64_bb_inplace(u16* __restrict__ d)
{
    __shared__ u16 t[64][65];
    u16* p = d + (size_t)blockIdx.x * 4096;
    const int tid = threadIdx.x;
    #pragma unroll
    for (int i = 0; i < 16; i++) { int idx = tid + 256 * i; t[idx >> 6][idx & 63] = p[idx]; }
    __syncthreads();
    #pragma unroll
    for (int i = 0; i < 16; i++) { int idx = tid + 256 * i; p[idx] = t[idx & 63][idx >> 6]; }
}

// ============== channel-last transpose: [64][4096] -> [4096][64] ==========
__global__ __launch_bounds__(256) void transpose_cl(
    const u16* __restrict__ src, u16* __restrict__ dst)
{
    __shared__ u16 t[64][65];
    const int s = blockIdx.x;
    const int batch = s >> 6, tile = s & 63;
    const u16* sp = src + (size_t)batch * 262144 + (size_t)tile * 64;
    u16* dp = dst + (size_t)batch * 262144 + (size_t)tile * 4096;
    const int tid = threadIdx.x;
    {
        const int c = tid >> 2, x0 = (tid & 3) * 16;
        *(uint4*)&t[c][x0]     = *(const uint4*)(sp + (size_t)c * 4096 + x0);
        *(uint4*)&t[c][x0 + 8] = *(const uint4*)(sp + (size_t)c * 4096 + x0 + 8);
    }
    __syncthreads();
    {
        const int x = tid >> 2, c0 = (tid & 3) * 16;
        u16 tmp[16];
        #pragma unroll
        for (int i = 0; i < 16; i++) tmp[i] = t[c0 + i][x];
        *(uint4*)&dp[(size_t)x * 64 + c0]     = *(uint4*)&tmp[0];
        *(uint4*)&dp[(size_t)x * 64 + c0 + 8] = *(uint4*)&tmp[8];
    }
}

// ======================= energies (MFMA) =======================
// e layout: (b,h,w,128) fp32. [0:64) = energy_H, [64:128) = energy_W.
// qc/kc: channel-last (b, h*64+w, 64c) bf16.
__global__ __launch_bounds__(256) void energy_h_mfma(
    const u16* __restrict__ qc, const u16* __restrict__ kc, float* __restrict__ e)
{
    __shared__ u16 Qs[64][72], Ks[64][72];  // [h][c] rows 144B
    const int w = blockIdx.x, b = blockIdx.y;
    const int tid = threadIdx.x;
    {
        const int row = tid >> 2, ch = (tid & 3) * 16;
        const size_t g = ((size_t)b * 4096 + (size_t)row * 64 + w) * 64 + ch;
        *(uint4*)&Qs[row][ch]     = *(const uint4*)(qc + g);
        *(uint4*)&Qs[row][ch + 8] = *(const uint4*)(qc + g + 8);
        *(uint4*)&Ks[row][ch]     = *(const uint4*)(kc + g);
        *(uint4*)&Ks[row][ch + 8] = *(const uint4*)(kc + g + 8);
    }
    __syncthreads();
    const int lane = tid & 63, wv = tid >> 6;
    const int mH = (wv & 1) * 32, nh = (wv >> 1) * 32;
    const int lr = lane & 15, lq = lane >> 4;
    f32x4 acc[2][2] = {};
    #pragma unroll
    for (int kt = 0; kt < 2; kt++) {
        const int k0 = kt * 32 + lq * 8;
        bf16x8 afr[2], bfr[2];
        #pragma unroll
        for (int i = 0; i < 2; i++) afr[i] = *(const bf16x8*)&Ks[mH + i * 16 + lr][k0];
        #pragma unroll
        for (int j = 0; j < 2; j++) bfr[j] = *(const bf16x8*)&Qs[nh + j * 16 + lr][k0];
        #pragma unroll
        for (int j = 0; j < 2; j++)
            #pragma unroll
            for (int i = 0; i < 2; i++)
                acc[i][j] = __builtin_amdgcn_mfma_f32_16x16x32_bf16(afr[i], bfr[j], acc[i][j], 0, 0, 0);
    }
    #pragma unroll
    for (int i = 0; i < 2; i++)
        #pragma unroll
        for (int j = 0; j < 2; j++) {
            const int h = nh + j * 16 + lr;
            const int Hp = mH + i * 16 + lq * 4;
            float4 v = make_float4(acc[i][j][0], acc[i][j][1], acc[i][j][2], acc[i][j][3]);
            *reinterpret_cast<float4*>(e + ((size_t)(b * 64 + h) * 64 + w) * 128 + Hp) = v;
        }
}

__global__ __launch_bounds__(256) void energy_w_mfma(
    const u16* __restrict__ qc, const u16* __restrict__ kc, float* __restrict__ e)
{
    __shared__ u16 Qs[64][72], Ks[64][72];  // [w][c]
    const int h = blockIdx.x, b = blockIdx.y;
    const int tid = threadIdx.x;
    {
        const int row = tid >> 2, ch = (tid & 3) * 16;
        const size_t g = ((size_t)b * 4096 + (size_t)h * 64 + row) * 64 + ch;
        *(uint4*)&Qs[row][ch]     = *(const uint4*)(qc + g);
        *(uint4*)&Qs[row][ch + 8] = *(const uint4*)(qc + g + 8);
        *(uint4*)&Ks[row][ch]     = *(const uint4*)(kc + g);
        *(uint4*)&Ks[row][ch + 8] = *(const uint4*)(kc + g + 8);
    }
    __syncthreads();
    const int lane = tid & 63, wv = tid >> 6;
    const int mW = (wv & 1) * 32, nw = (wv >> 1) * 32;
    const int lr = lane & 15, lq = lane >> 4;
    f32x4 acc[2][2] = {};
    #pragma unroll
    for (int kt = 0; kt < 2; kt++) {
        const int k0 = kt * 32 + lq * 8;
        bf16x8 afr[2], bfr[2];
        #pragma unroll
        for (int i = 0; i < 2; i++) afr[i] = *(const bf16x8*)&Ks[mW + i * 16 + lr][k0];
        #pragma unroll
        for (int j = 0; j < 2; j++) bfr[j] = *(const bf16x8*)&Qs[nw + j * 16 + lr][k0];
        #pragma unroll
        for (int j = 0; j < 2; j++)
            #pragma unroll
            for (int i = 0; i < 2; i++)
                acc[i][j] = __builtin_amdgcn_mfma_f32_16x16x32_bf16(afr[i], bfr[j], acc[i][j], 0, 0, 0);
    }
    #pragma unroll
    for (int i = 0; i < 2; i++)
        #pragma unroll
        for (int j = 0; j < 2; j++) {
            const int w = nw + j * 16 + lr;
            const int Wp = mW + i * 16 + lq * 4;
            float4 v = make_float4(acc[i][j][0], acc[i][j][1], acc[i][j][2], acc[i][j][3]);
            *reinterpret_cast<float4*>(e + ((size_t)(b * 64 + h) * 64 + w) * 128 + 64 + Wp) = v;
        }
}

// ============ softmax over 128, f32 in -> bf16 out ============
__global__ __launch_bounds__(256) void softmax128_bf(
    const float* __restrict__ e, u16* __restrict__ attb)
{
    const int pos = blockIdx.x * 4 + (threadIdx.x >> 6);
    const int l = threadIdx.x & 63;
    const float* p = e + (size_t)pos * 128;
    float v0 = p[l], v1 = p[l + 64];
    float m = fmaxf(v0, v1);
    #pragma unroll
    for (int o = 32; o > 0; o >>= 1) m = fmaxf(m, __shfl_xor(m, o, 64));
    float e0 = __expf(v0 - m), e1 = __expf(v1 - m);
    float s = e0 + e1;
    #pragma unroll
    for (int o = 32; o > 0; o >>= 1) s += __shfl_xor(s, o, 64);
    float inv = 1.0f / s;
    u16* q = attb + (size_t)pos * 128;
    q[l] = f2bu(e0 * inv);
    q[l + 64] = f2bu(e1 * inv);
}

// ======================= H-aggregation (MFMA, LDS-staged, in-place) =======
// P[b,c,w,h] = sum_H' vT[b,c,w,H'] * attH[b,h,w,H']  (round-2 config: c-tile
// 128, D row = c, col = h; bf16 out over the vT rows the block itself read).
// grid (mt=8, w=64, b=8). mt 0-3 -> a-side, 4-7 -> b-side.
__global__ __launch_bounds__(256) void agg_h_mfma(
    const u16* __restrict__ vTa, const u16* __restrict__ vTb,
    const u16* __restrict__ attb, u16* __restrict__ Pa, u16* __restrict__ Pb)
{
    __shared__ u16 Vs[128][72];  // [c][H'], rows 144 B
    __shared__ u16 As[64][72];   // [h][H']
    const int mt = blockIdx.x, w = blockIdx.y, b = blockIdx.z;
    const u16* vT = (mt < 4) ? vTa : vTb;
    u16*       P  = (mt < 4) ? Pa  : Pb;
    const int c0 = (mt & 3) * 128;
    const int tid = threadIdx.x;
    const u16* va = vT + ((size_t)(b * 512 + c0) * 64 + w) * 64;          // + c*4096 + H'
    const u16* ab = attb + ((size_t)b * 4096 + w) * 128;                  // + h*8192 + H'
    {
        const int r = tid >> 3, cB = (tid & 7) * 8;
        #pragma unroll
        for (int i = 0; i < 4; i++)
            *(uint4*)&Vs[r + 32 * i][cB] = *(const uint4*)(va + (size_t)(r + 32 * i) * 4096 + cB);
        #pragma unroll
        for (int i = 0; i < 2; i++)
            *(uint4*)&As[r + 32 * i][cB] = *(const uint4*)(ab + (size_t)(r + 32 * i) * 8192 + cB);
    }
    __syncthreads();
    const int lane = tid & 63, wv = tid >> 6;
    const int wm = (wv & 1) * 64, wn = (wv >> 1) * 32;
    const int lr = lane & 15, lq = lane >> 4;
    f32x4 acc[4][2] = {};
    #pragma unroll
    for (int kt = 0; kt < 2; kt++) {
        const int k0 = kt * 32 + lq * 8;
        bf16x8 afr[4], bfr[2];
        #pragma unroll
        for (int i = 0; i < 4; i++) afr[i] = *(const bf16x8*)&Vs[wm + i * 16 + lr][k0];
        #pragma unroll
        for (int j = 0; j < 2; j++) bfr[j] = *(const bf16x8*)&As[wn + j * 16 + lr][k0];
        #pragma unroll
        for (int j = 0; j < 2; j++)
            #pragma unroll
            for (int i = 0; i < 4; i++)
                acc[i][j] = __builtin_amdgcn_mfma_f32_16x16x32_bf16(afr[i], bfr[j], acc[i][j], 0, 0, 0);
    }
    // D: row(c within 16-tile) = lq*4+r, col(h) = lr
    #pragma unroll
    for (int i = 0; i < 4; i++)
        #pragma unroll
        for (int j = 0; j < 2; j++) {
            u16* pp = P + ((size_t)(b * 512 + c0 + wm + i * 16 + lq * 4) * 64 + w) * 64 + wn + j * 16 + lr;
            #pragma unroll
            for (int r = 0; r < 4; r++) pp[(size_t)r * 4096] = f2bu(acc[i][j][r]);
        }
}

// ======================= W-aggregation (MFMA, LDS-staged) + epilogue ======
// Round-2 config: c-tile 128, D row = c, col = w.
// y = g*(P + OutW) + x   (P in (b,c,h,w) bf16, x/y f32)
__global__ __launch_bounds__(256) void agg_w_mfma(
    const u16* __restrict__ v2, const u16* __restrict__ v1,
    const u16* __restrict__ P2, const u16* __restrict__ P1,
    const u16* __restrict__ attb,
    const float* __restrict__ x2, const float* __restrict__ x1,
    const float* __restrict__ gptr, float* __restrict__ out)
{
    __shared__ u16 Vs[128][72];  // [c][W']
    __shared__ u16 As[64][72];   // [w][W']
    const int mt = blockIdx.x, h = blockIdx.y, b = blockIdx.z;
    const u16* v = (mt < 4) ? v2 : v1;
    const u16* P = (mt < 4) ? P2 : P1;
    const float* x = (mt < 4) ? x2 : x1;
    float* y = out + ((mt < 4) ? 0 : PLANE);
    const int c0 = (mt & 3) * 128;
    const int tid = threadIdx.x;
    const u16* vb = v + (size_t)(b * 512 + c0) * 4096 + h * 64;           // + c*4096 + W'
    const u16* ab = attb + ((size_t)(b * 64 + h) * 64) * 128 + 64;        // + w*128 + W'
    {
        const int r = tid >> 3, cB = (tid & 7) * 8;
        #pragma unroll
        for (int i = 0; i < 4; i++)
            *(uint4*)&Vs[r + 32 * i][cB] = *(const uint4*)(vb + (size_t)(r + 32 * i) * 4096 + cB);
        #pragma unroll
        for (int i = 0; i < 2; i++)
            *(uint4*)&As[r + 32 * i][cB] = *(const uint4*)(ab + (size_t)(r + 32 * i) * 128 + cB);
    }
    __syncthreads();
    const int lane = tid & 63, wv = tid >> 6;
    const int wm = (wv & 1) * 64, wn = (wv >> 1) * 32;
    const int lr = lane & 15, lq = lane >> 4;
    f32x4 acc[4][2] = {};
    #pragma unroll
    for (int kt = 0; kt < 2; kt++) {
        const int k0 = kt * 32 + lq * 8;
        bf16x8 afr[4], bfr[2];
        #pragma unroll
        for (int i = 0; i < 4; i++) afr[i] = *(const bf16x8*)&Vs[wm + i * 16 + lr][k0];
        #pragma unroll
        for (int j = 0; j < 2; j++) bfr[j] = *(const bf16x8*)&As[wn + j * 16 + lr][k0];
        #pragma unroll
        for (int j = 0; j < 2; j++)
            #pragma unroll
            for (int i = 0; i < 4; i++)
                acc[i][j] = __builtin_amdgcn_mfma_f32_16x16x32_bf16(afr[i], bfr[j], acc[i][j], 0, 0, 0);
    }
    const float g = gptr[0];
    #pragma unroll
    for (int i = 0; i < 4; i++)
        #pragma unroll
        for (int j = 0; j < 2; j++) {
            size_t off = (size_t)(b * 512 + c0 + wm + i * 16 + lq * 4) * 4096
                       + (size_t)h * 64 + wn + j * 16 + lr;
            #pragma unroll
            for (int r = 0; r < 4; r++) {
                size_t o = off + (size_t)r * 4096;
                y[o] = g * (bfu2f(P[o]) + acc[i][j][r]) + x[o];
            }
        }
}

// ======================= host =======================
extern "C" void kernel_launch(void* const* d_in, const int* in_sizes, int n_in,
                              void* d_out, int out_size, void* d_ws, size_t ws_size,
                              hipStream_t stream)
{
    (void)in_sizes; (void)n_in; (void)out_size; (void)ws_size;
    const float* x2  = (const float*)d_in[0];
    const float* x1  = (const float*)d_in[1];
    const float* q_w = (const float*)d_in[2];
    const float* q_b = (const float*)d_in[3];
    const float* k_w = (const float*)d_in[4];
    const float* k_b = (const float*)d_in[5];
    const float* v_w = (const float*)d_in[6];
    const float* v_b = (const float*)d_in[7];
    const float* gm  = (const float*)d_in[8];

    // ws (MiB): v2 0-32 | v1 32-64 | attb 64-72 |
    //   scratch (dead after softmax): q 72-76 | k 76-80 | qc 80-84 | kc 84-88 | e 88-104
    //   vT2/P2 72-104, vT1/P1 104-136 (written after softmax; overlay scratch)
    // Total: 136 MiB.
    char* ws = (char*)d_ws;
    u16*   v2   = (u16*)(ws);
    u16*   v1   = (u16*)(ws + ((size_t)32  << 20));
    u16*   attb = (u16*)(ws + ((size_t)64  << 20));
    u16*   q    = (u16*)(ws + ((size_t)72  << 20));
    u16*   k    = (u16*)(ws + ((size_t)76  << 20));
    u16*   qc   = (u16*)(ws + ((size_t)80  << 20));
    u16*   kc   = (u16*)(ws + ((size_t)84  << 20));
    float* e    = (float*)(ws + ((size_t)88 << 20));
    u16*   vT2  = (u16*)(ws + ((size_t)72  << 20));  // overlays q..e (dead by then)
    u16*   vT1  = (u16*)(ws + ((size_t)104 << 20));
    float* out = (float*)d_out;

    dim3 blk(256);
    // merged projection: rows 0-639 from x2 -> q,k,v2; rows 640-1151 from x1 -> v1
    proj_mfma<<<dim3(256, 9), blk, 0, stream>>>(x2, x1, q_w, q_b, k_w, k_b,
                                                v_w, v_b, q, k, v2, v1);
    transpose_cl<<<1024, blk, 0, stream>>>(q, qc);          // q+k -> qc+kc (channel-last)
    energy_h_mfma<<<dim3(64, 8), blk, 0, stream>>>(qc, kc, e);
    energy_w_mfma<<<dim3(64, 8), blk, 0, stream>>>(qc, kc, e);
    softmax128_bf<<<8192, blk, 0, stream>>>(e, attb);       // e dead after this
    transpose64_bb<<<8192, blk, 0, stream>>>(v2, vT2);      // v2+v1 -> vT2+vT1
    agg_h_mfma<<<dim3(8, 64, 8), blk, 0, stream>>>(vT2, vT1, attb, vT2, vT1); // P over vT
    transpose64_bb_inplace<<<8192, blk, 0, stream>>>(vT2);  // P -> (b,c,h,w)
    agg_w_mfma<<<dim3(8, 64, 8), blk, 0, stream>>>(v2, v1, vT2, vT1, attb,
                                                   x2, x1, gm, out);
}

// Round 6
// 472.505 us; speedup vs baseline: 1.1228x; 1.0567x over previous
//
#include <hip/hip_runtime.h>
#include <cstdint>
#include <cstddef>

using u16 = unsigned short;
using u32 = unsigned int;

#define DI __device__ __forceinline__

typedef __attribute__((ext_vector_type(8))) short bf16x8;
typedef __attribute__((ext_vector_type(4))) float f32x4;

// bf16 <-> f32 helpers (bit math). Intermediates stored bf16 in ws.
DI float bfu2f(u16 u) { return __uint_as_float(((u32)u) << 16); }
DI u16 f2bu(float f) {  // round-to-nearest-even, finite inputs only
    u32 x = __float_as_uint(f);
    return (u16)((x + 0x7fffu + ((x >> 16) & 1u)) >> 16);
}
DI u32 pk2(float a, float b) { return (u32)f2bu(a) | ((u32)f2bu(b) << 16); }

constexpr int CIN = 512;
constexpr int HW  = 4096;              // 64*64
constexpr size_t PLANE = 16777216ull;  // 8*512*4096 elements per output tensor

// ============ prep: Wcat[640][512] bf16 (rows: 64 q_w | 64 k_w | 512 v_w) ===
__global__ __launch_bounds__(256) void wcat_bf16(
    const float* __restrict__ q_w, const float* __restrict__ k_w,
    const float* __restrict__ v_w, u16* __restrict__ Wcat)
{
    const int gid = blockIdx.x * 256 + threadIdx.x;   // 160 blocks -> 40960 thr
    const int e0 = gid * 8;                            // 640*512 elems
    const int row = e0 >> 9, col = e0 & 511;
    const float* src = (row < 64)  ? q_w + ((size_t)row << 9)
                     : (row < 128) ? k_w + ((size_t)(row - 64) << 9)
                                   : v_w + ((size_t)(row - 128) << 9);
    float4 f0 = *(const float4*)(src + col), f1 = *(const float4*)(src + col + 4);
    uint4 u = { pk2(f0.x, f0.y), pk2(f0.z, f0.w), pk2(f1.x, f1.y), pk2(f1.z, f1.w) };
    *(uint4*)(Wcat + e0) = u;
}

// ============ prep: x (b,512,4096) f32 -> XT (b,4096,512) bf16 ==============
// grid (64 hw-tiles, 16 (=2 tensors x 8 c-tiles), 8 b)
__global__ __launch_bounds__(256) void x_cl_bf16(
    const float* __restrict__ x2, const float* __restrict__ x1,
    u16* __restrict__ XT2, u16* __restrict__ XT1)
{
    __shared__ u16 t[64][72];
    const int st = blockIdx.x;
    const int ct = blockIdx.y & 7, sel = blockIdx.y >> 3;
    const int b  = blockIdx.z;
    const float* x = sel ? x1 : x2;
    u16* XT = sel ? XT1 : XT2;
    const int tid = threadIdx.x;
    const int c0 = ct * 64, s0 = st * 64;
    {
        const int c = tid >> 2, q = (tid & 3) * 16;
        const float* p = x + ((size_t)b * 512 + c0 + c) * 4096 + s0 + q;
        float4 f0 = *(const float4*)p,       f1 = *(const float4*)(p + 4);
        float4 f2 = *(const float4*)(p + 8), f3 = *(const float4*)(p + 12);
        uint4 u0 = { pk2(f0.x, f0.y), pk2(f0.z, f0.w), pk2(f1.x, f1.y), pk2(f1.z, f1.w) };
        uint4 u1 = { pk2(f2.x, f2.y), pk2(f2.z, f2.w), pk2(f3.x, f3.y), pk2(f3.z, f3.w) };
        *(uint4*)&t[c][q]     = u0;
        *(uint4*)&t[c][q + 8] = u1;
    }
    __syncthreads();
    {
        const int s = tid >> 2, q = (tid & 3) * 16;
        u16 tmp[16];
        #pragma unroll
        for (int i = 0; i < 16; i++) tmp[i] = t[q + i][s];
        u16* dp = XT + ((size_t)b * 4096 + s0 + s) * 512 + c0 + q;
        *(uint4*)&dp[0] = *(uint4*)&tmp[0];
        *(uint4*)&dp[8] = *(uint4*)&tmp[8];
    }
}

// ================= MFMA projection GEMM (bf16 operands, BK=64) ==============
// Rows m: [0,64)=q, [64,128)=k, [128,640)=v2 (from XT2), [640,1152)=v1 (XT1;
// Wcat rows 128-639 reused).  D[n][m]: A = XT rows (n over k), B = Wcat rows.
// grid (256 n-tiles, 9 m-tiles), block 256 (4 waves).
__global__ __launch_bounds__(256) void proj_mfma(
    const u16* __restrict__ XT2, const u16* __restrict__ XT1,
    const u16* __restrict__ Wcat,
    const float* __restrict__ q_b, const float* __restrict__ k_b,
    const float* __restrict__ v_b,
    u16* __restrict__ oq, u16* __restrict__ ok,
    u16* __restrict__ ov2, u16* __restrict__ ov1)
{
    __shared__ u16 Xl[128][72];   // [n][k], rows 144 B
    __shared__ u16 Wl[128][72];   // [m][k]
    const int tid = threadIdx.x;
    const int m0  = blockIdx.y * 128;          // 0..1151
    const int n0g = blockIdx.x * 128;
    const int b    = n0g >> 12;
    const int col0 = n0g & 4095;
    const u16* Xb = ((m0 < 640) ? XT2 : XT1) + ((size_t)b * 4096 + col0) * 512;
    const u16* Wb = Wcat + (size_t)((m0 < 640) ? m0 : m0 - 512) * 512;

    const int srow = tid >> 1, soff = (tid & 1) * 32;  // 2 thr/row, 64 B each
    const u16* xp = Xb + (size_t)srow * 512 + soff;
    const u16* wp = Wb + (size_t)srow * 512 + soff;

    const int lane = tid & 63, wv = tid >> 6;
    const int wn = (wv & 1) * 64;   // n-offset (D rows)
    const int wm = (wv >> 1) * 64;  // m-offset (D cols)
    const int lr = lane & 15, lq = lane >> 4;

    f32x4 acc[4][4] = {};           // [i: n-frag][j: m-frag]
    for (int kt = 0; kt < CIN; kt += 64) {
        #pragma unroll
        for (int t = 0; t < 4; t++) {
            *(uint4*)&Xl[srow][soff + 8 * t] = *(const uint4*)(xp + kt + 8 * t);
            *(uint4*)&Wl[srow][soff + 8 * t] = *(const uint4*)(wp + kt + 8 * t);
        }
        __syncthreads();
        #pragma unroll
        for (int ks = 0; ks < 2; ks++) {
            const int k0 = ks * 32 + lq * 8;
            bf16x8 a[4], bb[4];
            #pragma unroll
            for (int i = 0; i < 4; i++)
                a[i] = *(const bf16x8*)&Xl[wn + i * 16 + lr][k0];
            #pragma unroll
            for (int j = 0; j < 4; j++)
                bb[j] = *(const bf16x8*)&Wl[wm + j * 16 + lr][k0];
            #pragma unroll
            for (int j = 0; j < 4; j++)
                #pragma unroll
                for (int i = 0; i < 4; i++)
                    acc[i][j] = __builtin_amdgcn_mfma_f32_16x16x32_bf16(a[i], bb[j], acc[i][j], 0, 0, 0);
        }
        __syncthreads();
    }
    // epilogue: D row = n (lq*4+r consecutive), col = m (lr). Per-j routing.
    #pragma unroll
    for (int j = 0; j < 4; j++) {
        const int mbase = m0 + wm + j * 16;
        const float* bp; u16* op; int ch0, cc;
        if (mbase < 64)       { bp = q_b; op = oq;  ch0 = mbase;       cc = 64;  }
        else if (mbase < 128) { bp = k_b; op = ok;  ch0 = mbase - 64;  cc = 64;  }
        else if (mbase < 640) { bp = v_b; op = ov2; ch0 = mbase - 128; cc = 512; }
        else                  { bp = v_b; op = ov1; ch0 = mbase - 640; cc = 512; }
        const int ch = ch0 + lr;
        const float bias = bp[ch];
        u16* obase = op + ((size_t)b * cc + ch) * HW + col0 + wn + lq * 4;
        #pragma unroll
        for (int i = 0; i < 4; i++) {
            uint2 pkd = { pk2(acc[i][j][0] + bias, acc[i][j][1] + bias),
                          pk2(acc[i][j][2] + bias, acc[i][j][3] + bias) };
            *(uint2*)(obase + i * 16) = pkd;
        }
    }
}

// ============== 64x64 last-two-dims transpose (bf16 -> bf16) ==============
__global__ __launch_bounds__(256) void transpose64_bb(
    const u16* __restrict__ src, u16* __restrict__ dst)
{
    __shared__ u16 t[64][65];
    const size_t s = blockIdx.x;
    const u16* sp = src + s * 4096;
    u16* dp = dst + s * 4096;
    const int tid = threadIdx.x;
    #pragma unroll
    for (int i = 0; i < 16; i++) { int idx = tid + 256 * i; t[idx >> 6][idx & 63] = sp[idx]; }
    __syncthreads();
    #pragma unroll
    for (int i = 0; i < 16; i++) { int idx = tid + 256 * i; dp[idx] = t[idx & 63][idx >> 6]; }
}

// ============== in-place per-slice 64x64 bf16 transpose ==============
__global__ __launch_bounds__(256) void transpose64_bb_inplace(u16* __restrict__ d)
{
    __shared__ u16 t[64][65];
    u16* p = d + (size_t)blockIdx.x * 4096;
    const int tid = threadIdx.x;
    #pragma unroll
    for (int i = 0; i < 16; i++) { int idx = tid + 256 * i; t[idx >> 6][idx & 63] = p[idx]; }
    __syncthreads();
    #pragma unroll
    for (int i = 0; i < 16; i++) { int idx = tid + 256 * i; p[idx] = t[idx & 63][idx >> 6]; }
}

// ============== channel-last transpose: [64][4096] -> [4096][64] ==========
__global__ __launch_bounds__(256) void transpose_cl(
    const u16* __restrict__ src, u16* __restrict__ dst)
{
    __shared__ u16 t[64][65];
    const int s = blockIdx.x;
    const int batch = s >> 6, tile = s & 63;
    const u16* sp = src + (size_t)batch * 262144 + (size_t)tile * 64;
    u16* dp = dst + (size_t)batch * 262144 + (size_t)tile * 4096;
    const int tid = threadIdx.x;
    {
        const int c = tid >> 2, x0 = (tid & 3) * 16;
        *(uint4*)&t[c][x0]     = *(const uint4*)(sp + (size_t)c * 4096 + x0);
        *(uint4*)&t[c][x0 + 8] = *(const uint4*)(sp + (size_t)c * 4096 + x0 + 8);
    }
    __syncthreads();
    {
        const int x = tid >> 2, c0 = (tid & 3) * 16;
        u16 tmp[16];
        #pragma unroll
        for (int i = 0; i < 16; i++) tmp[i] = t[c0 + i][x];
        *(uint4*)&dp[(size_t)x * 64 + c0]     = *(uint4*)&tmp[0];
        *(uint4*)&dp[(size_t)x * 64 + c0 + 8] = *(uint4*)&tmp[8];
    }
}

// ======================= energies (MFMA) =======================
// e layout: (b,h,w,128) fp32. [0:64) = energy_H, [64:128) = energy_W.
// qc/kc: channel-last (b, h*64+w, 64c) bf16.
__global__ __launch_bounds__(256) void energy_h_mfma(
    const u16* __restrict__ qc, const u16* __restrict__ kc, float* __restrict__ e)
{
    __shared__ u16 Qs[64][72], Ks[64][72];  // [h][c] rows 144B
    const int w = blockIdx.x, b = blockIdx.y;
    const int tid = threadIdx.x;
    {
        const int row = tid >> 2, ch = (tid & 3) * 16;
        const size_t g = ((size_t)b * 4096 + (size_t)row * 64 + w) * 64 + ch;
        *(uint4*)&Qs[row][ch]     = *(const uint4*)(qc + g);
        *(uint4*)&Qs[row][ch + 8] = *(const uint4*)(qc + g + 8);
        *(uint4*)&Ks[row][ch]     = *(const uint4*)(kc + g);
        *(uint4*)&Ks[row][ch + 8] = *(const uint4*)(kc + g + 8);
    }
    __syncthreads();
    const int lane = tid & 63, wv = tid >> 6;
    const int mH = (wv & 1) * 32, nh = (wv >> 1) * 32;
    const int lr = lane & 15, lq = lane >> 4;
    f32x4 acc[2][2] = {};
    #pragma unroll
    for (int kt = 0; kt < 2; kt++) {
        const int k0 = kt * 32 + lq * 8;
        bf16x8 afr[2], bfr[2];
        #pragma unroll
        for (int i = 0; i < 2; i++) afr[i] = *(const bf16x8*)&Ks[mH + i * 16 + lr][k0];
        #pragma unroll
        for (int j = 0; j < 2; j++) bfr[j] = *(const bf16x8*)&Qs[nh + j * 16 + lr][k0];
        #pragma unroll
        for (int j = 0; j < 2; j++)
            #pragma unroll
            for (int i = 0; i < 2; i++)
                acc[i][j] = __builtin_amdgcn_mfma_f32_16x16x32_bf16(afr[i], bfr[j], acc[i][j], 0, 0, 0);
    }
    #pragma unroll
    for (int i = 0; i < 2; i++)
        #pragma unroll
        for (int j = 0; j < 2; j++) {
            const int h = nh + j * 16 + lr;
            const int Hp = mH + i * 16 + lq * 4;
            float4 v = make_float4(acc[i][j][0], acc[i][j][1], acc[i][j][2], acc[i][j][3]);
            *reinterpret_cast<float4*>(e + ((size_t)(b * 64 + h) * 64 + w) * 128 + Hp) = v;
        }
}

__global__ __launch_bounds__(256) void energy_w_mfma(
    const u16* __restrict__ qc, const u16* __restrict__ kc, float* __restrict__ e)
{
    __shared__ u16 Qs[64][72], Ks[64][72];  // [w][c]
    const int h = blockIdx.x, b = blockIdx.y;
    const int tid = threadIdx.x;
    {
        const int row = tid >> 2, ch = (tid & 3) * 16;
        const size_t g = ((size_t)b * 4096 + (size_t)h * 64 + row) * 64 + ch;
        *(uint4*)&Qs[row][ch]     = *(const uint4*)(qc + g);
        *(uint4*)&Qs[row][ch + 8] = *(const uint4*)(qc + g + 8);
        *(uint4*)&Ks[row][ch]     = *(const uint4*)(kc + g);
        *(uint4*)&Ks[row][ch + 8] = *(const uint4*)(kc + g + 8);
    }
    __syncthreads();
    const int lane = tid & 63, wv = tid >> 6;
    const int mW = (wv & 1) * 32, nw = (wv >> 1) * 32;
    const int lr = lane & 15, lq = lane >> 4;
    f32x4 acc[2][2] = {};
    #pragma unroll
    for (int kt = 0; kt < 2; kt++) {
        const int k0 = kt * 32 + lq * 8;
        bf16x8 afr[2], bfr[2];
        #pragma unroll
        for (int i = 0; i < 2; i++) afr[i] = *(const bf16x8*)&Ks[mW + i * 16 + lr][k0];
        #pragma unroll
        for (int j = 0; j < 2; j++) bfr[j] = *(const bf16x8*)&Qs[nw + j * 16 + lr][k0];
        #pragma unroll
        for (int j = 0; j < 2; j++)
            #pragma unroll
            for (int i = 0; i < 2; i++)
                acc[i][j] = __builtin_amdgcn_mfma_f32_16x16x32_bf16(afr[i], bfr[j], acc[i][j], 0, 0, 0);
    }
    #pragma unroll
    for (int i = 0; i < 2; i++)
        #pragma unroll
        for (int j = 0; j < 2; j++) {
            const int w = nw + j * 16 + lr;
            const int Wp = mW + i * 16 + lq * 4;
            float4 v = make_float4(acc[i][j][0], acc[i][j][1], acc[i][j][2], acc[i][j][3]);
            *reinterpret_cast<float4*>(e + ((size_t)(b * 64 + h) * 64 + w) * 128 + 64 + Wp) = v;
        }
}

// ============ softmax over 128, f32 in -> bf16 out ============
__global__ __launch_bounds__(256) void softmax128_bf(
    const float* __restrict__ e, u16* __restrict__ attb)
{
    const int pos = blockIdx.x * 4 + (threadIdx.x >> 6);
    const int l = threadIdx.x & 63;
    const float* p = e + (size_t)pos * 128;
    float v0 = p[l], v1 = p[l + 64];
    float m = fmaxf(v0, v1);
    #pragma unroll
    for (int o = 32; o > 0; o >>= 1) m = fmaxf(m, __shfl_xor(m, o, 64));
    float e0 = __expf(v0 - m), e1 = __expf(v1 - m);
    float s = e0 + e1;
    #pragma unroll
    for (int o = 32; o > 0; o >>= 1) s += __shfl_xor(s, o, 64);
    float inv = 1.0f / s;
    u16* q = attb + (size_t)pos * 128;
    q[l] = f2bu(e0 * inv);
    q[l + 64] = f2bu(e1 * inv);
}

// ======================= H-aggregation (MFMA, LDS-staged, in-place) =======
// P[b,c,w,h] = sum_H' vT[b,c,w,H'] * attH[b,h,w,H']  (round-2 config: c-tile
// 128, D row = c, col = h; bf16 out over the vT rows the block itself read).
// grid (mt=8, w=64, b=8). mt 0-3 -> a-side, 4-7 -> b-side.
__global__ __launch_bounds__(256) void agg_h_mfma(
    const u16* __restrict__ vTa, const u16* __restrict__ vTb,
    const u16* __restrict__ attb, u16* __restrict__ Pa, u16* __restrict__ Pb)
{
    __shared__ u16 Vs[128][72];  // [c][H'], rows 144 B
    __shared__ u16 As[64][72];   // [h][H']
    const int mt = blockIdx.x, w = blockIdx.y, b = blockIdx.z;
    const u16* vT = (mt < 4) ? vTa : vTb;
    u16*       P  = (mt < 4) ? Pa  : Pb;
    const int c0 = (mt & 3) * 128;
    const int tid = threadIdx.x;
    const u16* va = vT + ((size_t)(b * 512 + c0) * 64 + w) * 64;          // + c*4096 + H'
    const u16* ab = attb + ((size_t)b * 4096 + w) * 128;                  // + h*8192 + H'
    {
        const int r = tid >> 3, cB = (tid & 7) * 8;
        #pragma unroll
        for (int i = 0; i < 4; i++)
            *(uint4*)&Vs[r + 32 * i][cB] = *(const uint4*)(va + (size_t)(r + 32 * i) * 4096 + cB);
        #pragma unroll
        for (int i = 0; i < 2; i++)
            *(uint4*)&As[r + 32 * i][cB] = *(const uint4*)(ab + (size_t)(r + 32 * i) * 8192 + cB);
    }
    __syncthreads();
    const int lane = tid & 63, wv = tid >> 6;
    const int wm = (wv & 1) * 64, wn = (wv >> 1) * 32;
    const int lr = lane & 15, lq = lane >> 4;
    f32x4 acc[4][2] = {};
    #pragma unroll
    for (int kt = 0; kt < 2; kt++) {
        const int k0 = kt * 32 + lq * 8;
        bf16x8 afr[4], bfr[2];
        #pragma unroll
        for (int i = 0; i < 4; i++) afr[i] = *(const bf16x8*)&Vs[wm + i * 16 + lr][k0];
        #pragma unroll
        for (int j = 0; j < 2; j++) bfr[j] = *(const bf16x8*)&As[wn + j * 16 + lr][k0];
        #pragma unroll
        for (int j = 0; j < 2; j++)
            #pragma unroll
            for (int i = 0; i < 4; i++)
                acc[i][j] = __builtin_amdgcn_mfma_f32_16x16x32_bf16(afr[i], bfr[j], acc[i][j], 0, 0, 0);
    }
    // D: row(c within 16-tile) = lq*4+r, col(h) = lr
    #pragma unroll
    for (int i = 0; i < 4; i++)
        #pragma unroll
        for (int j = 0; j < 2; j++) {
            u16* pp = P + ((size_t)(b * 512 + c0 + wm + i * 16 + lq * 4) * 64 + w) * 64 + wn + j * 16 + lr;
            #pragma unroll
            for (int r = 0; r < 4; r++) pp[(size_t)r * 4096] = f2bu(acc[i][j][r]);
        }
}

// ======================= W-aggregation (MFMA, LDS-staged) + epilogue ======
// Round-2 config: c-tile 128, D row = c, col = w.
// y = g*(P + OutW) + x   (P in (b,c,h,w) bf16, x/y f32)
__global__ __launch_bounds__(256) void agg_w_mfma(
    const u16* __restrict__ v2, const u16* __restrict__ v1,
    const u16* __restrict__ P2, const u16* __restrict__ P1,
    const u16* __restrict__ attb,
    const float* __restrict__ x2, const float* __restrict__ x1,
    const float* __restrict__ gptr, float* __restrict__ out)
{
    __shared__ u16 Vs[128][72];  // [c][W']
    __shared__ u16 As[64][72];   // [w][W']
    const int mt = blockIdx.x, h = blockIdx.y, b = blockIdx.z;
    const u16* v = (mt < 4) ? v2 : v1;
    const u16* P = (mt < 4) ? P2 : P1;
    const float* x = (mt < 4) ? x2 : x1;
    float* y = out + ((mt < 4) ? 0 : PLANE);
    const int c0 = (mt & 3) * 128;
    const int tid = threadIdx.x;
    const u16* vb = v + (size_t)(b * 512 + c0) * 4096 + h * 64;           // + c*4096 + W'
    const u16* ab = attb + ((size_t)(b * 64 + h) * 64) * 128 + 64;        // + w*128 + W'
    {
        const int r = tid >> 3, cB = (tid & 7) * 8;
        #pragma unroll
        for (int i = 0; i < 4; i++)
            *(uint4*)&Vs[r + 32 * i][cB] = *(const uint4*)(vb + (size_t)(r + 32 * i) * 4096 + cB);
        #pragma unroll
        for (int i = 0; i < 2; i++)
            *(uint4*)&As[r + 32 * i][cB] = *(const uint4*)(ab + (size_t)(r + 32 * i) * 128 + cB);
    }
    __syncthreads();
    const int lane = tid & 63, wv = tid >> 6;
    const int wm = (wv & 1) * 64, wn = (wv >> 1) * 32;
    const int lr = lane & 15, lq = lane >> 4;
    f32x4 acc[4][2] = {};
    #pragma unroll
    for (int kt = 0; kt < 2; kt++) {
        const int k0 = kt * 32 + lq * 8;
        bf16x8 afr[4], bfr[2];
        #pragma unroll
        for (int i = 0; i < 4; i++) afr[i] = *(const bf16x8*)&Vs[wm + i * 16 + lr][k0];
        #pragma unroll
        for (int j = 0; j < 2; j++) bfr[j] = *(const bf16x8*)&As[wn + j * 16 + lr][k0];
        #pragma unroll
        for (int j = 0; j < 2; j++)
            #pragma unroll
            for (int i = 0; i < 4; i++)
                acc[i][j] = __builtin_amdgcn_mfma_f32_16x16x32_bf16(afr[i], bfr[j], acc[i][j], 0, 0, 0);
    }
    const float g = gptr[0];
    #pragma unroll
    for (int i = 0; i < 4; i++)
        #pragma unroll
        for (int j = 0; j < 2; j++) {
            size_t off = (size_t)(b * 512 + c0 + wm + i * 16 + lq * 4) * 4096
                       + (size_t)h * 64 + wn + j * 16 + lr;
            #pragma unroll
            for (int r = 0; r < 4; r++) {
                size_t o = off + (size_t)r * 4096;
                y[o] = g * (bfu2f(P[o]) + acc[i][j][r]) + x[o];
            }
        }
}

// ======================= host =======================
extern "C" void kernel_launch(void* const* d_in, const int* in_sizes, int n_in,
                              void* d_out, int out_size, void* d_ws, size_t ws_size,
                              hipStream_t stream)
{
    (void)in_sizes; (void)n_in; (void)out_size; (void)ws_size;
    const float* x2  = (const float*)d_in[0];
    const float* x1  = (const float*)d_in[1];
    const float* q_w = (const float*)d_in[2];
    const float* q_b = (const float*)d_in[3];
    const float* k_w = (const float*)d_in[4];
    const float* k_b = (const float*)d_in[5];
    const float* v_w = (const float*)d_in[6];
    const float* v_b = (const float*)d_in[7];
    const float* gm  = (const float*)d_in[8];

    // ws (MiB), time-disjoint overlays:
    //   v2 0-32 | v1 32-64 | attb 64-72 (after softmax)
    //   XT2 64-96 | XT1 96-128 | Wcat 128-130   (prep; dead after proj)
    //   qc 80-84 | kc 84-88 | e 88-104          (after proj; dead after softmax)
    //   vT2/P2 72-104 | vT1/P1 104-136          (after softmax)
    //   q 136-140 | k 140-144                   (proj out; dead after transpose_cl)
    // Max 144 MiB.
    char* ws = (char*)d_ws;
    u16*   v2   = (u16*)(ws);
    u16*   v1   = (u16*)(ws + ((size_t)32  << 20));
    u16*   attb = (u16*)(ws + ((size_t)64  << 20));
    u16*   XT2  = (u16*)(ws + ((size_t)64  << 20));
    u16*   XT1  = (u16*)(ws + ((size_t)96  << 20));
    u16*   Wcat = (u16*)(ws + ((size_t)128 << 20));
    u16*   qc   = (u16*)(ws + ((size_t)80  << 20));
    u16*   kc   = (u16*)(ws + ((size_t)84  << 20));
    float* e    = (float*)(ws + ((size_t)88 << 20));
    u16*   vT2  = (u16*)(ws + ((size_t)72  << 20));
    u16*   vT1  = (u16*)(ws + ((size_t)104 << 20));
    u16*   q    = (u16*)(ws + ((size_t)136 << 20));
    u16*   k    = (u16*)(ws + ((size_t)140 << 20));
    float* out = (float*)d_out;

    dim3 blk(256);
    wcat_bf16<<<160, blk, 0, stream>>>(q_w, k_w, v_w, Wcat);
    x_cl_bf16<<<dim3(64, 16, 8), blk, 0, stream>>>(x2, x1, XT2, XT1);
    proj_mfma<<<dim3(256, 9), blk, 0, stream>>>(XT2, XT1, Wcat, q_b, k_b, v_b,
                                                q, k, v2, v1);
    transpose_cl<<<1024, blk, 0, stream>>>(q, qc);          // q+k -> qc+kc
    energy_h_mfma<<<dim3(64, 8), blk, 0, stream>>>(qc, kc, e);
    energy_w_mfma<<<dim3(64, 8), blk, 0, stream>>>(qc, kc, e);
    softmax128_bf<<<8192, blk, 0, stream>>>(e, attb);       // e dead after this
    transpose64_bb<<<8192, blk, 0, stream>>>(v2, vT2);      // v2+v1 -> vT2+vT1
    agg_h_mfma<<<dim3(8, 64, 8), blk, 0, stream>>>(vT2, vT1, attb, vT2, vT1); // P over vT
    transpose64_bb_inplace<<<8192, blk, 0, stream>>>(vT2);  // P -> (b,c,h,w)
    agg_w_mfma<<<dim3(8, 64, 8), blk, 0, stream>>>(v2, v1, vT2, vT1, attb,
                                                   x2, x1, gm, out);
}